// Round 5
// baseline (645.402 us; speedup 1.0000x reference)
//
#include <hip/hip_runtime.h>

typedef _Float16 h8_t __attribute__((ext_vector_type(8)));
typedef _Float16 h4_t __attribute__((ext_vector_type(4)));
typedef float floatx4 __attribute__((ext_vector_type(4)));

__device__ __forceinline__ float leaky(float v) { return v >= 0.f ? v : 0.2f * v; }

// ---------------- CSR build ----------------
__global__ void hist_kernel(const int* __restrict__ dst, int E, int* __restrict__ cnt) {
    int e = blockIdx.x * blockDim.x + threadIdx.x;
    if (e < E) atomicAdd(&cnt[dst[e]], 1);
}

__global__ __launch_bounds__(256) void blocksum_kernel(const int* __restrict__ cnt, int N,
                                                       int* __restrict__ bsum) {
    __shared__ int red[256];
    int tid = threadIdx.x;
    int idx = blockIdx.x * 256 + tid;
    red[tid] = idx < N ? cnt[idx] + 1 : 0;
    __syncthreads();
#pragma unroll
    for (int off = 128; off >= 1; off >>= 1) {
        if (tid < off) red[tid] += red[tid + off];
        __syncthreads();
    }
    if (tid == 0) bsum[blockIdx.x] = red[0];
}

__global__ __launch_bounds__(256) void scanbsum_kernel(int* __restrict__ bsum, int nb,
                                                       int* __restrict__ total) {
    __shared__ int part[256];
    int tid = threadIdx.x;
    int per = (nb + 255) / 256;
    int s0 = tid * per, s1 = min(s0 + per, nb);
    int s = 0;
    for (int i = s0; i < s1; i++) s += bsum[i];
    part[tid] = s;
    __syncthreads();
    for (int off = 1; off < 256; off <<= 1) {
        int v = (tid >= off) ? part[tid - off] : 0;
        __syncthreads();
        part[tid] += v;
        __syncthreads();
    }
    int base = (tid == 0) ? 0 : part[tid - 1];
    for (int i = s0; i < s1; i++) {
        int v = bsum[i];
        bsum[i] = base;
        base += v;
    }
    if (tid == 255) *total = part[255];
}

__global__ __launch_bounds__(256) void rowptr_kernel(const int* __restrict__ cnt,
                                                     const int* __restrict__ bsum, int N,
                                                     int* __restrict__ row_ptr,
                                                     int* __restrict__ cursor) {
    __shared__ int lds[256];
    int tid = threadIdx.x;
    int idx = blockIdx.x * 256 + tid;
    int v = idx < N ? cnt[idx] + 1 : 0;
    lds[tid] = v;
    __syncthreads();
    for (int off = 1; off < 256; off <<= 1) {
        int t = (tid >= off) ? lds[tid - off] : 0;
        __syncthreads();
        lds[tid] += t;
        __syncthreads();
    }
    if (idx < N) {
        int p = bsum[blockIdx.x] + lds[tid] - v;
        row_ptr[idx] = p;
        cursor[idx] = p;
    }
}

// also emits dst_csr so edge weights can be computed edge-parallel in csr order
__global__ void scatter_kernel(const int* __restrict__ src, const int* __restrict__ dst,
                               int E, int N, int* __restrict__ cursor,
                               int* __restrict__ csr_src, int* __restrict__ dst_csr) {
    int e = blockIdx.x * blockDim.x + threadIdx.x;
    if (e >= E + N) return;
    int s, d;
    if (e < E) { s = src[e]; d = dst[e]; }
    else       { s = e - E;  d = s; }
    int pos = atomicAdd(&cursor[d], 1);
    csr_src[pos] = s;
    dst_csr[pos] = d;
}

// ---------------- per-edge softmax weights (H=4), head-major planes ----------------
__global__ __launch_bounds__(256) void edge_weights4_kernel(const int* __restrict__ csr_src,
                                                            const int* __restrict__ dst_csr,
                                                            const float* __restrict__ aS,
                                                            const float* __restrict__ aD,
                                                            float* __restrict__ wpl, int EN) {
    int i = blockIdx.x * blockDim.x + threadIdx.x;
    if (i >= EN) return;
    int s = csr_src[i], d = dst_csr[i];
    float4 as = *(const float4*)(aS + (size_t)s * 4);
    float4 ad = *(const float4*)(aD + (size_t)d * 4);
    wpl[i]            = __expf(fminf(leaky(as.x + ad.x), 60.f));
    wpl[EN + i]       = __expf(fminf(leaky(as.y + ad.y), 60.f));
    wpl[2 * EN + i]   = __expf(fminf(leaky(as.z + ad.z), 60.f));
    wpl[3 * EN + i]   = __expf(fminf(leaky(as.w + ad.w), 60.f));
}

// ---------------- fused weight prep ----------------
__global__ void prep_weights_all(const float* __restrict__ W_emb, const float* __restrict__ W0,
                                 const float* __restrict__ W1, const float* __restrict__ W2,
                                 _Float16* __restrict__ WeH, _Float16* __restrict__ WeL,
                                 _Float16* __restrict__ W0H, _Float16* __restrict__ W0L,
                                 _Float16* __restrict__ W1H, _Float16* __restrict__ W1L,
                                 _Float16* __restrict__ W2H, _Float16* __restrict__ W2L) {
    int which = blockIdx.y;
    const float* W;
    _Float16 *Wh, *Wl;
    int K, N;
    if (which == 0)      { W = W_emb; Wh = WeH; Wl = WeL; K = 128; N = 64; }
    else if (which == 1) { W = W0;    Wh = W0H; Wl = W0L; K = 64;  N = 256; }
    else if (which == 2) { W = W1;    Wh = W1H; Wl = W1L; K = 256; N = 256; }
    else                 { W = W2;    Wh = W2H; Wl = W2L; K = 256; N = 64; }
    int idx = blockIdx.x * blockDim.x + threadIdx.x;
    if (idx >= K * N) return;
    int k = idx / N, n = idx % N;
    float v = W[idx];
    _Float16 hi = (_Float16)v;
    _Float16 lo = (_Float16)(v - (float)hi);
    size_t o = ((size_t)(k >> 3) * N + n) * 8 + (k & 7);
    Wh[o] = hi; Wl[o] = lo;
}

// ---------------- embedding GEMM: direct-x A, full-B LDS stage, -> hi/lo planes ----------------
__global__ __launch_bounds__(256) void gemm_emb_kernel(
        const float* __restrict__ X,
        const _Float16* __restrict__ Bh, const _Float16* __restrict__ Bl,
        const float* __restrict__ bias,
        _Float16* __restrict__ Ph, _Float16* __restrict__ Pl,
        int Mpad, int M) {
    const int Nn = 64, K = 128;
    __shared__ _Float16 Bs[2][16][64][8];
    __shared__ _Float16 stH[4][16][72];
    __shared__ _Float16 stL[4][16][72];
    int tid = threadIdx.x;
    int wv = tid >> 6, lane = tid & 63;
    int m16 = lane & 15, quad = lane >> 4;
    int row0 = blockIdx.x * 128 + wv * 32;

#pragma unroll
    for (int cc = 0; cc < 8; cc++) {
        int c = tid + cc * 256;
        int plane = c >> 10, rem = c & 1023, q = rem >> 6, col = rem & 63;
        const _Float16* srcp = (plane ? Bl : Bh) + ((size_t)q * Nn + col) * 8;
        *reinterpret_cast<h8_t*>(&Bs[plane][q][col][0]) = *reinterpret_cast<const h8_t*>(srcp);
    }
    __syncthreads();

    floatx4 acc[2][4];
#pragma unroll
    for (int t = 0; t < 2; t++)
#pragma unroll
        for (int c = 0; c < 4; c++)
#pragma unroll
            for (int i = 0; i < 4; i++) acc[t][c][i] = 0.f;

    int r0 = row0 + m16, r1 = row0 + 16 + m16;
#pragma unroll
    for (int kt4 = 0; kt4 < 4; kt4++) {
        int kcol = kt4 * 32 + quad * 8;
        float vs0[8] = {0,0,0,0,0,0,0,0}, vs1[8] = {0,0,0,0,0,0,0,0};
        if (r0 < M) {
            const float4* p = (const float4*)(X + (size_t)r0 * K + kcol);
            float4 a = p[0], b = p[1];
            vs0[0]=a.x; vs0[1]=a.y; vs0[2]=a.z; vs0[3]=a.w;
            vs0[4]=b.x; vs0[5]=b.y; vs0[6]=b.z; vs0[7]=b.w;
        }
        if (r1 < M) {
            const float4* p = (const float4*)(X + (size_t)r1 * K + kcol);
            float4 a = p[0], b = p[1];
            vs1[0]=a.x; vs1[1]=a.y; vs1[2]=a.z; vs1[3]=a.w;
            vs1[4]=b.x; vs1[5]=b.y; vs1[6]=b.z; vs1[7]=b.w;
        }
        h8_t ah0, al0, ah1, al1;
#pragma unroll
        for (int j = 0; j < 8; j++) {
            _Float16 hi0 = (_Float16)vs0[j];
            ah0[j] = hi0; al0[j] = (_Float16)(vs0[j] - (float)hi0);
            _Float16 hi1 = (_Float16)vs1[j];
            ah1[j] = hi1; al1[j] = (_Float16)(vs1[j] - (float)hi1);
        }
        int kq = kt4 * 4 + quad;
#pragma unroll
        for (int c = 0; c < 4; c++) {
            h8_t bh = *reinterpret_cast<const h8_t*>(&Bs[0][kq][c * 16 + m16][0]);
            h8_t bl = *reinterpret_cast<const h8_t*>(&Bs[1][kq][c * 16 + m16][0]);
            acc[0][c] = __builtin_amdgcn_mfma_f32_16x16x32_f16(ah0, bh, acc[0][c], 0, 0, 0);
            acc[1][c] = __builtin_amdgcn_mfma_f32_16x16x32_f16(ah1, bh, acc[1][c], 0, 0, 0);
            acc[0][c] = __builtin_amdgcn_mfma_f32_16x16x32_f16(ah0, bl, acc[0][c], 0, 0, 0);
            acc[1][c] = __builtin_amdgcn_mfma_f32_16x16x32_f16(ah1, bl, acc[1][c], 0, 0, 0);
            acc[0][c] = __builtin_amdgcn_mfma_f32_16x16x32_f16(al0, bh, acc[0][c], 0, 0, 0);
            acc[1][c] = __builtin_amdgcn_mfma_f32_16x16x32_f16(al1, bh, acc[1][c], 0, 0, 0);
        }
    }

    // epilogue: st buffers are wave-local -> no barriers needed
#pragma unroll
    for (int t = 0; t < 2; t++) {
#pragma unroll
        for (int c = 0; c < 4; c++) {
            float bv = bias[c * 16 + m16];
#pragma unroll
            for (int i = 0; i < 4; i++) {
                float v = fmaxf(acc[t][c][i] + bv, 0.f);
                _Float16 hi = (_Float16)v;
                stH[wv][quad * 4 + i][c * 16 + m16] = hi;
                stL[wv][quad * 4 + i][c * 16 + m16] = (_Float16)(v - (float)hi);
            }
        }
        int rowChunk = row0 + t * 16;
#pragma unroll
        for (int it = 0; it < 2; it++) {
            int lid = it * 64 + lane;
            int kg = lid >> 4, rloc = lid & 15;
            h8_t vh = *reinterpret_cast<const h8_t*>(&stH[wv][rloc][kg * 8]);
            h8_t vl = *reinterpret_cast<const h8_t*>(&stL[wv][rloc][kg * 8]);
            size_t o = ((size_t)kg * Mpad + rowChunk + rloc) * 8;
            *reinterpret_cast<h8_t*>(Ph + o) = vh;
            *reinterpret_cast<h8_t*>(Pl + o) = vl;
        }
    }
}

// ---------------- GAT GEMM layer0 (K=64, full-B stage) + fused alphas ----------------
// hOut written group-major: [grp=col>>5][Mpad][32ch] for XCD-sliced aggregation
__global__ __launch_bounds__(256) void gemm_gat0_kernel(
        const _Float16* __restrict__ Ah, const _Float16* __restrict__ Al,
        const _Float16* __restrict__ Bh, const _Float16* __restrict__ Bl,
        const float* __restrict__ a_src, const float* __restrict__ a_dst,
        _Float16* __restrict__ hOut, float* __restrict__ aS, float* __restrict__ aD,
        int Mpad, int M) {
    const int Nn = 256;
    __shared__ _Float16 Bs[2][8][128][8];
    __shared__ _Float16 st[4][16][136];
    int tid = threadIdx.x;
    int wv = tid >> 6, lane = tid & 63;
    int m16 = lane & 15, quad = lane >> 4;
    int row0 = blockIdx.y * 128 + wv * 32;
    int colBase = blockIdx.x * 128;
    size_t kqbase = (size_t)colBase * 8;

#pragma unroll
    for (int cc = 0; cc < 8; cc++) {
        int c = tid + cc * 256;
        int plane = c >> 10, rem = c & 1023, q = rem >> 7, col = rem & 127;
        const _Float16* srcp = (plane ? Bl : Bh) + kqbase + ((size_t)q * Nn + col) * 8;
        *reinterpret_cast<h8_t*>(&Bs[plane][q][col][0]) = *reinterpret_cast<const h8_t*>(srcp);
    }
    __syncthreads();

    floatx4 acc[2][8];
#pragma unroll
    for (int t = 0; t < 2; t++)
#pragma unroll
        for (int c = 0; c < 8; c++)
#pragma unroll
            for (int i = 0; i < 4; i++) acc[t][c][i] = 0.f;

#pragma unroll
    for (int kt = 0; kt < 2; kt++) {
        int kq = kt * 4 + quad;
        size_t aoff = ((size_t)kq * Mpad + row0 + m16) * 8;
        h8_t ah0 = *reinterpret_cast<const h8_t*>(Ah + aoff);
        h8_t ah1 = *reinterpret_cast<const h8_t*>(Ah + aoff + 128);
        h8_t al0 = *reinterpret_cast<const h8_t*>(Al + aoff);
        h8_t al1 = *reinterpret_cast<const h8_t*>(Al + aoff + 128);
#pragma unroll
        for (int c = 0; c < 8; c++) {
            h8_t bh = *reinterpret_cast<const h8_t*>(&Bs[0][kq][c * 16 + m16][0]);
            h8_t bl = *reinterpret_cast<const h8_t*>(&Bs[1][kq][c * 16 + m16][0]);
            acc[0][c] = __builtin_amdgcn_mfma_f32_16x16x32_f16(ah0, bh, acc[0][c], 0, 0, 0);
            acc[1][c] = __builtin_amdgcn_mfma_f32_16x16x32_f16(ah1, bh, acc[1][c], 0, 0, 0);
            acc[0][c] = __builtin_amdgcn_mfma_f32_16x16x32_f16(ah0, bl, acc[0][c], 0, 0, 0);
            acc[1][c] = __builtin_amdgcn_mfma_f32_16x16x32_f16(ah1, bl, acc[1][c], 0, 0, 0);
            acc[0][c] = __builtin_amdgcn_mfma_f32_16x16x32_f16(al0, bh, acc[0][c], 0, 0, 0);
            acc[1][c] = __builtin_amdgcn_mfma_f32_16x16x32_f16(al1, bh, acc[1][c], 0, 0, 0);
        }
    }

    float asv[8], adv[8];
#pragma unroll
    for (int c = 0; c < 8; c++) {
        asv[c] = a_src[colBase + c * 16 + m16];
        adv[c] = a_dst[colBase + c * 16 + m16];
    }
    int hb = colBase >> 6;
#pragma unroll
    for (int t = 0; t < 2; t++) {
#pragma unroll
        for (int i = 0; i < 4; i++) {
            int r = row0 + t * 16 + quad * 4 + i;
            float s0 = 0.f, d0 = 0.f, s1 = 0.f, d1 = 0.f;
#pragma unroll
            for (int c = 0; c < 8; c++) {
                float v = acc[t][c][i];
                if (c < 4) { s0 += v * asv[c]; d0 += v * adv[c]; }
                else       { s1 += v * asv[c]; d1 += v * adv[c]; }
            }
#pragma unroll
            for (int off = 1; off < 16; off <<= 1) {
                s0 += __shfl_xor(s0, off);
                d0 += __shfl_xor(d0, off);
                s1 += __shfl_xor(s1, off);
                d1 += __shfl_xor(d1, off);
            }
            if (m16 == 0 && r < M) {
                aS[r * 4 + hb] = s0;     aD[r * 4 + hb] = d0;
                aS[r * 4 + hb + 1] = s1; aD[r * 4 + hb + 1] = d1;
            }
        }
    }

    // wave-local epilogue (no barriers) -> group-major planes
#pragma unroll
    for (int t = 0; t < 2; t++) {
#pragma unroll
        for (int c = 0; c < 8; c++)
#pragma unroll
            for (int i = 0; i < 4; i++)
                st[wv][quad * 4 + i][c * 16 + m16] = (_Float16)acc[t][c][i];
        int rowChunk = row0 + t * 16;
#pragma unroll
        for (int it = 0; it < 4; it++) {
            int lid = it * 64 + lane;
            int rloc = lid >> 4, u = lid & 15;
            h8_t v = *reinterpret_cast<const h8_t*>(&st[wv][rloc][u * 8]);
            int col = colBase + u * 8;
            int grp = col >> 5, c32 = col & 31;
            *reinterpret_cast<h8_t*>(hOut + ((size_t)grp * Mpad + rowChunk + rloc) * 32 + c32) = v;
        }
    }
}

// ---------------- GAT GEMM layer1 (K=256, double-buffered) + fused alphas ----------------
__global__ __launch_bounds__(256) void gemm_gat1_kernel(
        const _Float16* __restrict__ Ah, const _Float16* __restrict__ Al,
        const _Float16* __restrict__ Bh, const _Float16* __restrict__ Bl,
        const float* __restrict__ a_src, const float* __restrict__ a_dst,
        _Float16* __restrict__ hOut, float* __restrict__ aS, float* __restrict__ aD,
        int Mpad, int M, int K) {
    const int Nn = 256;
    __shared__ _Float16 Bs[2][4][128][8];
    __shared__ _Float16 st[4][16][136];
    int tid = threadIdx.x;
    int wv = tid >> 6, lane = tid & 63;
    int m16 = lane & 15, quad = lane >> 4;
    int row0 = blockIdx.y * 128 + wv * 32;
    int colBase = blockIdx.x * 128;

    floatx4 acc[2][8];
#pragma unroll
    for (int t = 0; t < 2; t++)
#pragma unroll
        for (int c = 0; c < 8; c++)
#pragma unroll
            for (int i = 0; i < 4; i++) acc[t][c][i] = 0.f;

    // loop-invariant staging decode
    int sPlane[4], sQ[4], sCol[4];
    const _Float16* sBase[4];
#pragma unroll
    for (int cc = 0; cc < 4; cc++) {
        int c = tid + cc * 256;
        sPlane[cc] = c >> 9;
        int rem = c & 511;
        sQ[cc] = rem >> 7;
        sCol[cc] = rem & 127;
        sBase[cc] = (sPlane[cc] ? Bl : Bh) + ((size_t)sQ[cc] * Nn + sCol[cc]) * 8;
    }

    size_t aoff = ((size_t)quad * Mpad + row0 + m16) * 8;
    size_t kqbase = (size_t)colBase * 8;
    const size_t aStep = (size_t)Mpad * 32;
    const size_t bStep = (size_t)Nn * 32;

    // prologue: load first A + B tiles into registers
    h8_t aR[4], bR[4];
    aR[0] = *reinterpret_cast<const h8_t*>(Ah + aoff);
    aR[1] = *reinterpret_cast<const h8_t*>(Ah + aoff + 128);
    aR[2] = *reinterpret_cast<const h8_t*>(Al + aoff);
    aR[3] = *reinterpret_cast<const h8_t*>(Al + aoff + 128);
#pragma unroll
    for (int cc = 0; cc < 4; cc++)
        bR[cc] = *reinterpret_cast<const h8_t*>(sBase[cc] + kqbase);

    for (int kt = 0; kt < K; kt += 32) {
        // write staged B regs -> LDS
#pragma unroll
        for (int cc = 0; cc < 4; cc++)
            *reinterpret_cast<h8_t*>(&Bs[sPlane[cc]][sQ[cc]][sCol[cc]][0]) = bR[cc];
        __syncthreads();
        // prefetch next iteration (flies during MFMA below)
        h8_t aN[4], bN[4];
        bool more = (kt + 32) < K;
        if (more) {
            aoff += aStep; kqbase += bStep;
            aN[0] = *reinterpret_cast<const h8_t*>(Ah + aoff);
            aN[1] = *reinterpret_cast<const h8_t*>(Ah + aoff + 128);
            aN[2] = *reinterpret_cast<const h8_t*>(Al + aoff);
            aN[3] = *reinterpret_cast<const h8_t*>(Al + aoff + 128);
#pragma unroll
            for (int cc = 0; cc < 4; cc++)
                bN[cc] = *reinterpret_cast<const h8_t*>(sBase[cc] + kqbase);
        }
#pragma unroll
        for (int c = 0; c < 8; c++) {
            h8_t bh = *reinterpret_cast<const h8_t*>(&Bs[0][quad][c * 16 + m16][0]);
            h8_t bl = *reinterpret_cast<const h8_t*>(&Bs[1][quad][c * 16 + m16][0]);
            acc[0][c] = __builtin_amdgcn_mfma_f32_16x16x32_f16(aR[0], bh, acc[0][c], 0, 0, 0);
            acc[1][c] = __builtin_amdgcn_mfma_f32_16x16x32_f16(aR[1], bh, acc[1][c], 0, 0, 0);
            acc[0][c] = __builtin_amdgcn_mfma_f32_16x16x32_f16(aR[0], bl, acc[0][c], 0, 0, 0);
            acc[1][c] = __builtin_amdgcn_mfma_f32_16x16x32_f16(aR[1], bl, acc[1][c], 0, 0, 0);
            acc[0][c] = __builtin_amdgcn_mfma_f32_16x16x32_f16(aR[2], bh, acc[0][c], 0, 0, 0);
            acc[1][c] = __builtin_amdgcn_mfma_f32_16x16x32_f16(aR[3], bh, acc[1][c], 0, 0, 0);
        }
        __syncthreads();
        if (more) {
#pragma unroll
            for (int j = 0; j < 4; j++) { aR[j] = aN[j]; bR[j] = bN[j]; }
        }
    }

    float asv[8], adv[8];
#pragma unroll
    for (int c = 0; c < 8; c++) {
        asv[c] = a_src[colBase + c * 16 + m16];
        adv[c] = a_dst[colBase + c * 16 + m16];
    }
    int hb = colBase >> 6;
#pragma unroll
    for (int t = 0; t < 2; t++) {
#pragma unroll
        for (int i = 0; i < 4; i++) {
            int r = row0 + t * 16 + quad * 4 + i;
            float s0 = 0.f, d0 = 0.f, s1 = 0.f, d1 = 0.f;
#pragma unroll
            for (int c = 0; c < 8; c++) {
                float v = acc[t][c][i];
                if (c < 4) { s0 += v * asv[c]; d0 += v * adv[c]; }
                else       { s1 += v * asv[c]; d1 += v * adv[c]; }
            }
#pragma unroll
            for (int off = 1; off < 16; off <<= 1) {
                s0 += __shfl_xor(s0, off);
                d0 += __shfl_xor(d0, off);
                s1 += __shfl_xor(s1, off);
                d1 += __shfl_xor(d1, off);
            }
            if (m16 == 0 && r < M) {
                aS[r * 4 + hb] = s0;     aD[r * 4 + hb] = d0;
                aS[r * 4 + hb + 1] = s1; aD[r * 4 + hb + 1] = d1;
            }
        }
    }

    // wave-local epilogue (no barriers) -> group-major planes
#pragma unroll
    for (int t = 0; t < 2; t++) {
#pragma unroll
        for (int c = 0; c < 8; c++)
#pragma unroll
            for (int i = 0; i < 4; i++)
                st[wv][quad * 4 + i][c * 16 + m16] = (_Float16)acc[t][c][i];
        int rowChunk = row0 + t * 16;
#pragma unroll
        for (int it = 0; it < 4; it++) {
            int lid = it * 64 + lane;
            int rloc = lid >> 4, u = lid & 15;
            h8_t v = *reinterpret_cast<const h8_t*>(&st[wv][rloc][u * 8]);
            int col = colBase + u * 8;
            int grp = col >> 5, c32 = col & 31;
            *reinterpret_cast<h8_t*>(hOut + ((size_t)grp * Mpad + rowChunk + rloc) * 32 + c32) = v;
        }
    }
}

// ---------------- layer-2 GEMM (Nn=64, K=256, double-buffered) + fused alphas ----------------
__global__ __launch_bounds__(256) void gemm_l2_kernel(
        const _Float16* __restrict__ Ah, const _Float16* __restrict__ Al,
        const _Float16* __restrict__ Bh, const _Float16* __restrict__ Bl,
        const float* __restrict__ a_src, const float* __restrict__ a_dst,
        _Float16* __restrict__ hOut, float* __restrict__ aS, float* __restrict__ aD,
        int Mpad, int M, int K) {
    const int Nn = 64;
    __shared__ _Float16 Bs[2][4][64][8];
    __shared__ _Float16 st[4][16][72];
    int tid = threadIdx.x;
    int wv = tid >> 6, lane = tid & 63;
    int m16 = lane & 15, quad = lane >> 4;
    int row0 = blockIdx.x * 128 + wv * 32;

    floatx4 acc[2][4];
#pragma unroll
    for (int t = 0; t < 2; t++)
#pragma unroll
        for (int c = 0; c < 4; c++)
#pragma unroll
            for (int i = 0; i < 4; i++) acc[t][c][i] = 0.f;

    int sPlane[2], sQ[2], sCol[2];
    const _Float16* sBase[2];
#pragma unroll
    for (int cc = 0; cc < 2; cc++) {
        int c = tid + cc * 256;
        sPlane[cc] = c >> 8;
        int rem = c & 255;
        sQ[cc] = rem >> 6;
        sCol[cc] = rem & 63;
        sBase[cc] = (sPlane[cc] ? Bl : Bh) + ((size_t)sQ[cc] * Nn + sCol[cc]) * 8;
    }

    size_t aoff = ((size_t)quad * Mpad + row0 + m16) * 8;
    size_t kqbase = 0;
    const size_t aStep = (size_t)Mpad * 32;
    const size_t bStep = (size_t)Nn * 32;

    h8_t aR[4], bR[2];
    aR[0] = *reinterpret_cast<const h8_t*>(Ah + aoff);
    aR[1] = *reinterpret_cast<const h8_t*>(Ah + aoff + 128);
    aR[2] = *reinterpret_cast<const h8_t*>(Al + aoff);
    aR[3] = *reinterpret_cast<const h8_t*>(Al + aoff + 128);
#pragma unroll
    for (int cc = 0; cc < 2; cc++)
        bR[cc] = *reinterpret_cast<const h8_t*>(sBase[cc] + kqbase);

    for (int kt = 0; kt < K; kt += 32) {
#pragma unroll
        for (int cc = 0; cc < 2; cc++)
            *reinterpret_cast<h8_t*>(&Bs[sPlane[cc]][sQ[cc]][sCol[cc]][0]) = bR[cc];
        __syncthreads();
        h8_t aN[4], bN[2];
        bool more = (kt + 32) < K;
        if (more) {
            aoff += aStep; kqbase += bStep;
            aN[0] = *reinterpret_cast<const h8_t*>(Ah + aoff);
            aN[1] = *reinterpret_cast<const h8_t*>(Ah + aoff + 128);
            aN[2] = *reinterpret_cast<const h8_t*>(Al + aoff);
            aN[3] = *reinterpret_cast<const h8_t*>(Al + aoff + 128);
#pragma unroll
            for (int cc = 0; cc < 2; cc++)
                bN[cc] = *reinterpret_cast<const h8_t*>(sBase[cc] + kqbase);
        }
#pragma unroll
        for (int c = 0; c < 4; c++) {
            h8_t bh = *reinterpret_cast<const h8_t*>(&Bs[0][quad][c * 16 + m16][0]);
            h8_t bl = *reinterpret_cast<const h8_t*>(&Bs[1][quad][c * 16 + m16][0]);
            acc[0][c] = __builtin_amdgcn_mfma_f32_16x16x32_f16(aR[0], bh, acc[0][c], 0, 0, 0);
            acc[1][c] = __builtin_amdgcn_mfma_f32_16x16x32_f16(aR[1], bh, acc[1][c], 0, 0, 0);
            acc[0][c] = __builtin_amdgcn_mfma_f32_16x16x32_f16(aR[0], bl, acc[0][c], 0, 0, 0);
            acc[1][c] = __builtin_amdgcn_mfma_f32_16x16x32_f16(aR[1], bl, acc[1][c], 0, 0, 0);
            acc[0][c] = __builtin_amdgcn_mfma_f32_16x16x32_f16(aR[2], bh, acc[0][c], 0, 0, 0);
            acc[1][c] = __builtin_amdgcn_mfma_f32_16x16x32_f16(aR[3], bh, acc[1][c], 0, 0, 0);
        }
        __syncthreads();
        if (more) {
            aR[0] = aN[0]; aR[1] = aN[1]; aR[2] = aN[2]; aR[3] = aN[3];
            bR[0] = bN[0]; bR[1] = bN[1];
        }
    }

    float asv[4], adv[4];
#pragma unroll
    for (int c = 0; c < 4; c++) {
        asv[c] = a_src[c * 16 + m16];
        adv[c] = a_dst[c * 16 + m16];
    }
#pragma unroll
    for (int t = 0; t < 2; t++) {
#pragma unroll
        for (int i = 0; i < 4; i++) {
            int r = row0 + t * 16 + quad * 4 + i;
            float s0 = 0.f, d0 = 0.f;
#pragma unroll
            for (int c = 0; c < 4; c++) {
                float v = acc[t][c][i];
                s0 += v * asv[c]; d0 += v * adv[c];
            }
#pragma unroll
            for (int off = 1; off < 16; off <<= 1) {
                s0 += __shfl_xor(s0, off);
                d0 += __shfl_xor(d0, off);
            }
            if (m16 == 0 && r < M) { aS[r] = s0; aD[r] = d0; }
        }
    }

    // wave-local epilogue (no barriers)
#pragma unroll
    for (int t = 0; t < 2; t++) {
#pragma unroll
        for (int c = 0; c < 4; c++)
#pragma unroll
            for (int i = 0; i < 4; i++)
                st[wv][quad * 4 + i][c * 16 + m16] = (_Float16)acc[t][c][i];
        int rowChunk = row0 + t * 16;
#pragma unroll
        for (int it = 0; it < 2; it++) {
            int lid = it * 64 + lane;
            int rloc = lid >> 3, u = lid & 7;
            h8_t v = *reinterpret_cast<const h8_t*>(&st[wv][rloc][u * 8]);
            *reinterpret_cast<h8_t*>(hOut + (size_t)(rowChunk + rloc) * 64 + u * 8) = v;
        }
    }
}

// ---------------- aggregation H=4: 8-way XCD-sliced, precomputed weights ----------------
// hsrc planes [grp][Mpad][32ch]; grp = blockIdx&7 -> fixed XCD (round-robin) so each
// XCD's gather set is one 3.2MB plane (L2-resident). No exp/LDS: weights streamed
// from head-major wpl planes. wave = (node,grp); 16 edge-slots x 4 lanes x 16B.
template <int TAG>
__global__ __launch_bounds__(256) void aggregate4_kernel(const _Float16* __restrict__ hsrc,
                                                         const float* __restrict__ wpl,
                                                         const int* __restrict__ row_ptr,
                                                         const int* __restrict__ csr_src,
                                                         const float* __restrict__ bias,
                                                         _Float16* __restrict__ outH,
                                                         _Float16* __restrict__ outL,
                                                         int N, int Mpad, int EN) {
    int tid = threadIdx.x;
    int wv = tid >> 6, lane = tid & 63;
    int grp = blockIdx.x & 7;
    int node = (blockIdx.x >> 3) * 4 + wv;
    if (node >= N) return;
    int rs = row_ptr[node], re = row_ptr[node + 1];
    int slot = lane >> 2, lp = lane & 3;
    int head = grp >> 1;
    const float* wp = wpl + (size_t)head * EN;
    const char* hbase = (const char*)hsrc + (size_t)grp * Mpad * 64;

    float den = 0.f;
    float acc8[8] = {0.f, 0.f, 0.f, 0.f, 0.f, 0.f, 0.f, 0.f};
    for (int base = rs; base < re; base += 16) {
        int i = base + slot;
        if (i < re) {
            int s = csr_src[i];
            float w = wp[i];
            den += w;
            h8_t hv = *reinterpret_cast<const h8_t*>(hbase + (size_t)s * 64 + lp * 16);
#pragma unroll
            for (int k = 0; k < 8; k++) acc8[k] += w * (float)hv[k];
        }
    }
    // reduce over slot bits (lane bits 2..5)
#pragma unroll
    for (int k = 0; k < 8; k++) {
        acc8[k] += __shfl_xor(acc8[k], 4);
        acc8[k] += __shfl_xor(acc8[k], 8);
        acc8[k] += __shfl_xor(acc8[k], 16);
        acc8[k] += __shfl_xor(acc8[k], 32);
    }
    den += __shfl_xor(den, 4);
    den += __shfl_xor(den, 8);
    den += __shfl_xor(den, 16);
    den += __shfl_xor(den, 32);
    if (slot == 0) {
        float inv = 1.f / (den + 1e-16f);
        int ch0 = grp * 32 + lp * 8;
        float4 b0 = *(const float4*)(bias + ch0);
        float4 b1 = *(const float4*)(bias + ch0 + 4);
        float bv[8] = {b0.x, b0.y, b0.z, b0.w, b1.x, b1.y, b1.z, b1.w};
        h8_t hv, lv;
#pragma unroll
        for (int k = 0; k < 8; k++) {
            float v = fmaxf(acc8[k] * inv + bv[k], 0.f);
            _Float16 hi = (_Float16)v;
            hv[k] = hi;
            lv[k] = (_Float16)(v - (float)hi);
        }
        int kq = grp * 4 + lp;
        size_t o = ((size_t)kq * Mpad + node) * 8;
        *reinterpret_cast<h8_t*>(outH + o) = hv;
        *reinterpret_cast<h8_t*>(outL + o) = lv;
    }
}

// ---------------- fused aggregation H=1 + head MLP ----------------
__global__ __launch_bounds__(256) void agg1_mlp_kernel(const _Float16* __restrict__ hsrc,
                                                       const float* __restrict__ alpha_s,
                                                       const float* __restrict__ alpha_d,
                                                       const int* __restrict__ row_ptr,
                                                       const int* __restrict__ csr_src,
                                                       const float* __restrict__ bias,
                                                       const float* __restrict__ Wo1,
                                                       const float* __restrict__ bo1,
                                                       const float* __restrict__ Wo2,
                                                       const float* __restrict__ bo2,
                                                       float* __restrict__ out, int N) {
    __shared__ float wlds[4][64];
    __shared__ int   slds[4][64];
    __shared__ float hrow[4][64];
    __shared__ float w1s[64 * 32];
    __shared__ float w2s[32];
    __shared__ float b1s[32];
    int tid = threadIdx.x;
#pragma unroll
    for (int i = 0; i < 8; i++) w1s[tid + i * 256] = Wo1[tid + i * 256];
    if (tid < 32) { w2s[tid] = Wo2[tid]; b1s[tid] = bo1[tid]; }
    __syncthreads();

    int wv = tid >> 6, lane = tid & 63;
    int node = blockIdx.x * 4 + wv;
    if (node >= N) return;
    int rs = row_ptr[node], re = row_ptr[node + 1];
    float ad = alpha_d[node];
    int slot = lane >> 3, lp = lane & 7;
    int gbyte = lp * 16;

    float den = 0.f;
    float acc8[8] = {0.f, 0.f, 0.f, 0.f, 0.f, 0.f, 0.f, 0.f};
    const char* hbase = (const char*)hsrc;
    float* wp = &wlds[wv][0];
    int*   sp = &slds[wv][0];
    for (int base = rs; base < re; base += 64) {
        int i = base + lane;
        float w = 0.f;
        int off = 0;
        if (i < re) {
            int s = __builtin_nontemporal_load(csr_src + i);
            w = __expf(fminf(leaky(alpha_s[s] + ad), 60.f));
            off = s * 128;
        }
        den += w;
        sp[lane] = off;
        wp[lane] = w;
        int cnt = min(64, re - base);
#pragma unroll 2
        for (int j = slot; j < cnt; j += 8) {
            float wj = wp[j];
            h8_t hv = *reinterpret_cast<const h8_t*>(hbase + sp[j] + gbyte);
#pragma unroll
            for (int k = 0; k < 8; k++) acc8[k] += wj * (float)hv[k];
        }
    }
#pragma unroll
    for (int k = 0; k < 8; k++) {
        acc8[k] += __shfl_xor(acc8[k], 8);
        acc8[k] += __shfl_xor(acc8[k], 16);
        acc8[k] += __shfl_xor(acc8[k], 32);
    }
#pragma unroll
    for (int off = 32; off >= 1; off >>= 1) den += __shfl_xor(den, off);
    if (slot == 0) {
        float inv = 1.f / (den + 1e-16f);
        int cbase = lp * 8;
#pragma unroll
        for (int k = 0; k < 8; k++)
            hrow[wv][cbase + k] = acc8[k] * inv + bias[cbase + k];
    }
    int j = lane & 31;
    float a = b1s[j];
#pragma unroll 4
    for (int k = 0; k < 64; k++) a += hrow[wv][k] * w1s[k * 32 + j];
    a = fmaxf(a, 0.f);
    float p = a * w2s[j];
#pragma unroll
    for (int off = 16; off >= 1; off >>= 1) p += __shfl_xor(p, off);
    if (lane == 0) out[node] = p + bo2[0];
}

// ---------------- launch ----------------
extern "C" void kernel_launch(void* const* d_in, const int* in_sizes, int n_in,
                              void* d_out, int out_size, void* d_ws, size_t ws_size,
                              hipStream_t stream) {
    const float* x     = (const float*)d_in[0];
    const float* W_emb = (const float*)d_in[1];
    const float* b_emb = (const float*)d_in[2];
    const float* W0    = (const float*)d_in[3];
    const float* as0   = (const float*)d_in[4];
    const float* ad0   = (const float*)d_in[5];
    const float* b0    = (const float*)d_in[6];
    const float* W1    = (const float*)d_in[7];
    const float* as1   = (const float*)d_in[8];
    const float* ad1   = (const float*)d_in[9];
    const float* b1    = (const float*)d_in[10];
    const float* W2    = (const float*)d_in[11];
    const float* as2   = (const float*)d_in[12];
    const float* ad2   = (const float*)d_in[13];
    const float* b2    = (const float*)d_in[14];
    const float* Wo1   = (const float*)d_in[15];
    const float* bo1   = (const float*)d_in[16];
    const float* Wo2   = (const float*)d_in[17];
    const float* bo2   = (const float*)d_in[18];
    const int* eidx    = (const int*)d_in[19];

    const int N = in_sizes[0] / 128;
    const int E = in_sizes[19] / 2;
    const int* esrc = eidx;
    const int* edst = eidx + E;
    const int gmB  = (N + 127) / 128;
    const int Mpad = gmB * 128;
    const int nb   = (N + 255) / 256;
    const int EN   = E + N;

    char* w = (char*)d_ws;
    auto alloc = [&](size_t bytes) {
        char* p = w;
        w += (bytes + 255) & ~(size_t)255;
        return (void*)p;
    };
    _Float16* hOut = (_Float16*)alloc((size_t)Mpad * 256 * 2);
    _Float16* PHh  = (_Float16*)alloc((size_t)Mpad * 256 * 2);
    _Float16* PHl  = (_Float16*)alloc((size_t)Mpad * 256 * 2);
    float* aS      = (float*)alloc((size_t)N * 4 * 4);
    float* aD      = (float*)alloc((size_t)N * 4 * 4);
    int*   row_ptr = (int*)alloc((size_t)(N + 1) * 4);
    int*   cursor  = (int*)alloc((size_t)N * 4);
    int*   cnt     = (int*)alloc((size_t)N * 4);
    int*   bsum    = (int*)alloc((size_t)nb * 4);
    int*   csr     = (int*)alloc((size_t)EN * 4);
    int*   dstc    = (int*)alloc((size_t)EN * 4);
    float* wpl     = (float*)alloc((size_t)EN * 4 * 4);
    _Float16* WeH  = (_Float16*)alloc(128 * 64 * 2);
    _Float16* WeL  = (_Float16*)alloc(128 * 64 * 2);
    _Float16* W0H  = (_Float16*)alloc(64 * 256 * 2);
    _Float16* W0L  = (_Float16*)alloc(64 * 256 * 2);
    _Float16* W1H  = (_Float16*)alloc(256 * 256 * 2);
    _Float16* W1L  = (_Float16*)alloc(256 * 256 * 2);
    _Float16* W2H  = (_Float16*)alloc(256 * 64 * 2);
    _Float16* W2L  = (_Float16*)alloc(256 * 64 * 2);

    // CSR build (multi-block scan)
    hipMemsetAsync(cnt, 0, (size_t)N * 4, stream);
    hist_kernel<<<(E + 255) / 256, 256, 0, stream>>>(edst, E, cnt);
    blocksum_kernel<<<nb, 256, 0, stream>>>(cnt, N, bsum);
    scanbsum_kernel<<<1, 256, 0, stream>>>(bsum, nb, row_ptr + N);
    rowptr_kernel<<<nb, 256, 0, stream>>>(cnt, bsum, N, row_ptr, cursor);
    scatter_kernel<<<(EN + 255) / 256, 256, 0, stream>>>(esrc, edst, E, N, cursor, csr, dstc);

    // weight planes (fused single launch)
    prep_weights_all<<<dim3(256, 4), 256, 0, stream>>>(W_emb, W0, W1, W2,
                                                       WeH, WeL, W0H, W0L, W1H, W1L, W2H, W2L);

    int gn4 = (N + 3) / 4;
    int gnAgg = gn4 * 8;         // 8 channel groups, blockIdx&7 -> XCD
    int gnEW  = (EN + 255) / 256;

    // embedding
    gemm_emb_kernel<<<dim3(gmB, 1), 256, 0, stream>>>(x, WeH, WeL, b_emb, PHh, PHl, Mpad, N);

    // GAT layer 0
    gemm_gat0_kernel<<<dim3(2, gmB), 256, 0, stream>>>(PHh, PHl, W0H, W0L, as0, ad0, hOut, aS, aD, Mpad, N);
    edge_weights4_kernel<<<gnEW, 256, 0, stream>>>(csr, dstc, aS, aD, wpl, EN);
    aggregate4_kernel<0><<<gnAgg, 256, 0, stream>>>(hOut, wpl, row_ptr, csr, b0, PHh, PHl, N, Mpad, EN);

    // GAT layer 1
    gemm_gat1_kernel<<<dim3(2, gmB), 256, 0, stream>>>(PHh, PHl, W1H, W1L, as1, ad1, hOut, aS, aD, Mpad, N, 256);
    edge_weights4_kernel<<<gnEW, 256, 0, stream>>>(csr, dstc, aS, aD, wpl, EN);
    aggregate4_kernel<1><<<gnAgg, 256, 0, stream>>>(hOut, wpl, row_ptr, csr, b1, PHh, PHl, N, Mpad, EN);

    // GAT layer 2 + fused head MLP
    gemm_l2_kernel<<<dim3(gmB, 1), 256, 0, stream>>>(PHh, PHl, W2H, W2L, as2, ad2, hOut, aS, aD, Mpad, N, 256);
    agg1_mlp_kernel<<<gn4, 256, 0, stream>>>(hOut, aS, aD, row_ptr, csr, b2,
                                             Wo1, bo1, Wo2, bo2, (float*)d_out, N);
}

// Round 7
// 475.778 us; speedup vs baseline: 1.3565x; 1.3565x over previous
//
#include <hip/hip_runtime.h>

typedef _Float16 h8_t __attribute__((ext_vector_type(8)));
typedef _Float16 h4_t __attribute__((ext_vector_type(4)));
typedef float floatx4 __attribute__((ext_vector_type(4)));

__device__ __forceinline__ float leaky(float v) { return v >= 0.f ? v : 0.2f * v; }

// ---------------- CSR build ----------------
__global__ void hist_kernel(const int* __restrict__ dst, int E, int* __restrict__ cnt) {
    int e = blockIdx.x * blockDim.x + threadIdx.x;
    if (e < E) atomicAdd(&cnt[dst[e]], 1);
}

__global__ __launch_bounds__(256) void blocksum_kernel(const int* __restrict__ cnt, int N,
                                                       int* __restrict__ bsum) {
    __shared__ int red[256];
    int tid = threadIdx.x;
    int idx = blockIdx.x * 256 + tid;
    red[tid] = idx < N ? cnt[idx] + 1 : 0;
    __syncthreads();
#pragma unroll
    for (int off = 128; off >= 1; off >>= 1) {
        if (tid < off) red[tid] += red[tid + off];
        __syncthreads();
    }
    if (tid == 0) bsum[blockIdx.x] = red[0];
}

__global__ __launch_bounds__(256) void scanbsum_kernel(int* __restrict__ bsum, int nb,
                                                       int* __restrict__ total) {
    __shared__ int part[256];
    int tid = threadIdx.x;
    int per = (nb + 255) / 256;
    int s0 = tid * per, s1 = min(s0 + per, nb);
    int s = 0;
    for (int i = s0; i < s1; i++) s += bsum[i];
    part[tid] = s;
    __syncthreads();
    for (int off = 1; off < 256; off <<= 1) {
        int v = (tid >= off) ? part[tid - off] : 0;
        __syncthreads();
        part[tid] += v;
        __syncthreads();
    }
    int base = (tid == 0) ? 0 : part[tid - 1];
    for (int i = s0; i < s1; i++) {
        int v = bsum[i];
        bsum[i] = base;
        base += v;
    }
    if (tid == 255) *total = part[255];
}

__global__ __launch_bounds__(256) void rowptr_kernel(const int* __restrict__ cnt,
                                                     const int* __restrict__ bsum, int N,
                                                     int* __restrict__ row_ptr,
                                                     int* __restrict__ cursor) {
    __shared__ int lds[256];
    int tid = threadIdx.x;
    int idx = blockIdx.x * 256 + tid;
    int v = idx < N ? cnt[idx] + 1 : 0;
    lds[tid] = v;
    __syncthreads();
    for (int off = 1; off < 256; off <<= 1) {
        int t = (tid >= off) ? lds[tid - off] : 0;
        __syncthreads();
        lds[tid] += t;
        __syncthreads();
    }
    if (idx < N) {
        int p = bsum[blockIdx.x] + lds[tid] - v;
        row_ptr[idx] = p;
        cursor[idx] = p;
    }
}

__global__ void scatter_kernel(const int* __restrict__ src, const int* __restrict__ dst,
                               int E, int N, int* __restrict__ cursor, int* __restrict__ csr_src) {
    int e = blockIdx.x * blockDim.x + threadIdx.x;
    if (e >= E + N) return;
    int s, d;
    if (e < E) { s = src[e]; d = dst[e]; }
    else       { s = e - E;  d = s; }
    int pos = atomicAdd(&cursor[d], 1);
    csr_src[pos] = s;
}

// ---------------- fused weight prep ----------------
__global__ void prep_weights_all(const float* __restrict__ W_emb, const float* __restrict__ W0,
                                 const float* __restrict__ W1, const float* __restrict__ W2,
                                 _Float16* __restrict__ WeH, _Float16* __restrict__ WeL,
                                 _Float16* __restrict__ W0H, _Float16* __restrict__ W0L,
                                 _Float16* __restrict__ W1H, _Float16* __restrict__ W1L,
                                 _Float16* __restrict__ W2H, _Float16* __restrict__ W2L) {
    int which = blockIdx.y;
    const float* W;
    _Float16 *Wh, *Wl;
    int K, N;
    if (which == 0)      { W = W_emb; Wh = WeH; Wl = WeL; K = 128; N = 64; }
    else if (which == 1) { W = W0;    Wh = W0H; Wl = W0L; K = 64;  N = 256; }
    else if (which == 2) { W = W1;    Wh = W1H; Wl = W1L; K = 256; N = 256; }
    else                 { W = W2;    Wh = W2H; Wl = W2L; K = 256; N = 64; }
    int idx = blockIdx.x * blockDim.x + threadIdx.x;
    if (idx >= K * N) return;
    int k = idx / N, n = idx % N;
    float v = W[idx];
    _Float16 hi = (_Float16)v;
    _Float16 lo = (_Float16)(v - (float)hi);
    size_t o = ((size_t)(k >> 3) * N + n) * 8 + (k & 7);
    Wh[o] = hi; Wl[o] = lo;
}

// ---------------- embedding GEMM: 64-row blocks (3 blocks/CU vs 1.5) ----------------
__global__ __launch_bounds__(256) void gemm_emb_kernel(
        const float* __restrict__ X,
        const _Float16* __restrict__ Bh, const _Float16* __restrict__ Bl,
        const float* __restrict__ bias,
        _Float16* __restrict__ Ph, _Float16* __restrict__ Pl,
        int Mpad, int M) {
    const int Nn = 64, K = 128;
    __shared__ _Float16 Bs[2][16][64][8];
    __shared__ _Float16 stH[4][16][72];
    __shared__ _Float16 stL[4][16][72];
    int tid = threadIdx.x;
    int wv = tid >> 6, lane = tid & 63;
    int m16 = lane & 15, quad = lane >> 4;
    int row0 = blockIdx.x * 64 + wv * 16;

#pragma unroll
    for (int cc = 0; cc < 8; cc++) {
        int c = tid + cc * 256;
        int plane = c >> 10, rem = c & 1023, q = rem >> 6, col = rem & 63;
        const _Float16* srcp = (plane ? Bl : Bh) + ((size_t)q * Nn + col) * 8;
        *reinterpret_cast<h8_t*>(&Bs[plane][q][col][0]) = *reinterpret_cast<const h8_t*>(srcp);
    }
    __syncthreads();

    floatx4 acc[4];
#pragma unroll
    for (int c = 0; c < 4; c++)
#pragma unroll
        for (int i = 0; i < 4; i++) acc[c][i] = 0.f;

    int r0 = row0 + m16;
#pragma unroll
    for (int kt4 = 0; kt4 < 4; kt4++) {
        int kcol = kt4 * 32 + quad * 8;
        float vs0[8] = {0,0,0,0,0,0,0,0};
        if (r0 < M) {
            const float4* p = (const float4*)(X + (size_t)r0 * K + kcol);
            float4 a = p[0], b = p[1];
            vs0[0]=a.x; vs0[1]=a.y; vs0[2]=a.z; vs0[3]=a.w;
            vs0[4]=b.x; vs0[5]=b.y; vs0[6]=b.z; vs0[7]=b.w;
        }
        h8_t ah0, al0;
#pragma unroll
        for (int j = 0; j < 8; j++) {
            _Float16 hi0 = (_Float16)vs0[j];
            ah0[j] = hi0; al0[j] = (_Float16)(vs0[j] - (float)hi0);
        }
        int kq = kt4 * 4 + quad;
#pragma unroll
        for (int c = 0; c < 4; c++) {
            h8_t bh = *reinterpret_cast<const h8_t*>(&Bs[0][kq][c * 16 + m16][0]);
            h8_t bl = *reinterpret_cast<const h8_t*>(&Bs[1][kq][c * 16 + m16][0]);
            acc[c] = __builtin_amdgcn_mfma_f32_16x16x32_f16(ah0, bh, acc[c], 0, 0, 0);
            acc[c] = __builtin_amdgcn_mfma_f32_16x16x32_f16(ah0, bl, acc[c], 0, 0, 0);
            acc[c] = __builtin_amdgcn_mfma_f32_16x16x32_f16(al0, bh, acc[c], 0, 0, 0);
        }
    }

    // epilogue: st buffers are wave-local -> no barriers needed
#pragma unroll
    for (int c = 0; c < 4; c++) {
        float bv = bias[c * 16 + m16];
#pragma unroll
        for (int i = 0; i < 4; i++) {
            float v = fmaxf(acc[c][i] + bv, 0.f);
            _Float16 hi = (_Float16)v;
            stH[wv][quad * 4 + i][c * 16 + m16] = hi;
            stL[wv][quad * 4 + i][c * 16 + m16] = (_Float16)(v - (float)hi);
        }
    }
#pragma unroll
    for (int it = 0; it < 2; it++) {
        int lid = it * 64 + lane;
        int kg = lid >> 4, rloc = lid & 15;
        h8_t vh = *reinterpret_cast<const h8_t*>(&stH[wv][rloc][kg * 8]);
        h8_t vl = *reinterpret_cast<const h8_t*>(&stL[wv][rloc][kg * 8]);
        size_t o = ((size_t)kg * Mpad + row0 + rloc) * 8;
        *reinterpret_cast<h8_t*>(Ph + o) = vh;
        *reinterpret_cast<h8_t*>(Pl + o) = vl;
    }
}

// ---------------- GAT GEMM layer0 (K=64, full-B stage) + fused alphas ----------------
__global__ __launch_bounds__(256) void gemm_gat0_kernel(
        const _Float16* __restrict__ Ah, const _Float16* __restrict__ Al,
        const _Float16* __restrict__ Bh, const _Float16* __restrict__ Bl,
        const float* __restrict__ a_src, const float* __restrict__ a_dst,
        _Float16* __restrict__ hOut, float* __restrict__ aS, float* __restrict__ aD,
        int Mpad, int M) {
    const int Nn = 256;
    __shared__ _Float16 Bs[2][8][128][8];
    __shared__ _Float16 st[4][16][136];
    int tid = threadIdx.x;
    int wv = tid >> 6, lane = tid & 63;
    int m16 = lane & 15, quad = lane >> 4;
    int row0 = blockIdx.x * 128 + wv * 32;
    int colBase = blockIdx.y * 128;
    size_t kqbase = (size_t)colBase * 8;

#pragma unroll
    for (int cc = 0; cc < 8; cc++) {
        int c = tid + cc * 256;
        int plane = c >> 10, rem = c & 1023, q = rem >> 7, col = rem & 127;
        const _Float16* srcp = (plane ? Bl : Bh) + kqbase + ((size_t)q * Nn + col) * 8;
        *reinterpret_cast<h8_t*>(&Bs[plane][q][col][0]) = *reinterpret_cast<const h8_t*>(srcp);
    }
    __syncthreads();

    floatx4 acc[2][8];
#pragma unroll
    for (int t = 0; t < 2; t++)
#pragma unroll
        for (int c = 0; c < 8; c++)
#pragma unroll
            for (int i = 0; i < 4; i++) acc[t][c][i] = 0.f;

#pragma unroll
    for (int kt = 0; kt < 2; kt++) {
        int kq = kt * 4 + quad;
        size_t aoff = ((size_t)kq * Mpad + row0 + m16) * 8;
        h8_t ah0 = *reinterpret_cast<const h8_t*>(Ah + aoff);
        h8_t ah1 = *reinterpret_cast<const h8_t*>(Ah + aoff + 128);
        h8_t al0 = *reinterpret_cast<const h8_t*>(Al + aoff);
        h8_t al1 = *reinterpret_cast<const h8_t*>(Al + aoff + 128);
#pragma unroll
        for (int c = 0; c < 8; c++) {
            h8_t bh = *reinterpret_cast<const h8_t*>(&Bs[0][kq][c * 16 + m16][0]);
            h8_t bl = *reinterpret_cast<const h8_t*>(&Bs[1][kq][c * 16 + m16][0]);
            acc[0][c] = __builtin_amdgcn_mfma_f32_16x16x32_f16(ah0, bh, acc[0][c], 0, 0, 0);
            acc[1][c] = __builtin_amdgcn_mfma_f32_16x16x32_f16(ah1, bh, acc[1][c], 0, 0, 0);
            acc[0][c] = __builtin_amdgcn_mfma_f32_16x16x32_f16(ah0, bl, acc[0][c], 0, 0, 0);
            acc[1][c] = __builtin_amdgcn_mfma_f32_16x16x32_f16(ah1, bl, acc[1][c], 0, 0, 0);
            acc[0][c] = __builtin_amdgcn_mfma_f32_16x16x32_f16(al0, bh, acc[0][c], 0, 0, 0);
            acc[1][c] = __builtin_amdgcn_mfma_f32_16x16x32_f16(al1, bh, acc[1][c], 0, 0, 0);
        }
    }

    float asv[8], adv[8];
#pragma unroll
    for (int c = 0; c < 8; c++) {
        asv[c] = a_src[colBase + c * 16 + m16];
        adv[c] = a_dst[colBase + c * 16 + m16];
    }
    int hb = colBase >> 6;
#pragma unroll
    for (int t = 0; t < 2; t++) {
#pragma unroll
        for (int i = 0; i < 4; i++) {
            int r = row0 + t * 16 + quad * 4 + i;
            float s0 = 0.f, d0 = 0.f, s1 = 0.f, d1 = 0.f;
#pragma unroll
            for (int c = 0; c < 8; c++) {
                float v = acc[t][c][i];
                if (c < 4) { s0 += v * asv[c]; d0 += v * adv[c]; }
                else       { s1 += v * asv[c]; d1 += v * adv[c]; }
            }
#pragma unroll
            for (int off = 1; off < 16; off <<= 1) {
                s0 += __shfl_xor(s0, off);
                d0 += __shfl_xor(d0, off);
                s1 += __shfl_xor(s1, off);
                d1 += __shfl_xor(d1, off);
            }
            if (m16 == 0 && r < M) {
                aS[r * 4 + hb] = s0;     aD[r * 4 + hb] = d0;
                aS[r * 4 + hb + 1] = s1; aD[r * 4 + hb + 1] = d1;
            }
        }
    }

    // wave-local epilogue (no barriers)
#pragma unroll
    for (int t = 0; t < 2; t++) {
#pragma unroll
        for (int c = 0; c < 8; c++)
#pragma unroll
            for (int i = 0; i < 4; i++)
                st[wv][quad * 4 + i][c * 16 + m16] = (_Float16)acc[t][c][i];
        int rowChunk = row0 + t * 16;
#pragma unroll
        for (int it = 0; it < 4; it++) {
            int lid = it * 64 + lane;
            int rloc = lid >> 4, u = lid & 15;
            h8_t v = *reinterpret_cast<const h8_t*>(&st[wv][rloc][u * 8]);
            *reinterpret_cast<h8_t*>(hOut + (size_t)(rowChunk + rloc) * 256 + colBase + u * 8) = v;
        }
    }
}

// ---------------- GAT GEMM layer1 (K=256, double-buffered) + fused alphas ----------------
__global__ __launch_bounds__(256) void gemm_gat1_kernel(
        const _Float16* __restrict__ Ah, const _Float16* __restrict__ Al,
        const _Float16* __restrict__ Bh, const _Float16* __restrict__ Bl,
        const float* __restrict__ a_src, const float* __restrict__ a_dst,
        _Float16* __restrict__ hOut, float* __restrict__ aS, float* __restrict__ aD,
        int Mpad, int M, int K) {
    const int Nn = 256;
    __shared__ _Float16 Bs[2][4][128][8];
    __shared__ _Float16 st[4][16][136];
    int tid = threadIdx.x;
    int wv = tid >> 6, lane = tid & 63;
    int m16 = lane & 15, quad = lane >> 4;
    int row0 = blockIdx.x * 128 + wv * 32;
    int colBase = blockIdx.y * 128;

    floatx4 acc[2][8];
#pragma unroll
    for (int t = 0; t < 2; t++)
#pragma unroll
        for (int c = 0; c < 8; c++)
#pragma unroll
            for (int i = 0; i < 4; i++) acc[t][c][i] = 0.f;

    // loop-invariant staging decode
    int sPlane[4], sQ[4], sCol[4];
    const _Float16* sBase[4];
#pragma unroll
    for (int cc = 0; cc < 4; cc++) {
        int c = tid + cc * 256;
        sPlane[cc] = c >> 9;
        int rem = c & 511;
        sQ[cc] = rem >> 7;
        sCol[cc] = rem & 127;
        sBase[cc] = (sPlane[cc] ? Bl : Bh) + ((size_t)sQ[cc] * Nn + sCol[cc]) * 8;
    }

    size_t aoff = ((size_t)quad * Mpad + row0 + m16) * 8;
    size_t kqbase = (size_t)colBase * 8;
    const size_t aStep = (size_t)Mpad * 32;
    const size_t bStep = (size_t)Nn * 32;

    // prologue: load first A + B tiles into registers
    h8_t aR[4], bR[4];
    aR[0] = *reinterpret_cast<const h8_t*>(Ah + aoff);
    aR[1] = *reinterpret_cast<const h8_t*>(Ah + aoff + 128);
    aR[2] = *reinterpret_cast<const h8_t*>(Al + aoff);
    aR[3] = *reinterpret_cast<const h8_t*>(Al + aoff + 128);
#pragma unroll
    for (int cc = 0; cc < 4; cc++)
        bR[cc] = *reinterpret_cast<const h8_t*>(sBase[cc] + kqbase);

    for (int kt = 0; kt < K; kt += 32) {
        // write staged B regs -> LDS
#pragma unroll
        for (int cc = 0; cc < 4; cc++)
            *reinterpret_cast<h8_t*>(&Bs[sPlane[cc]][sQ[cc]][sCol[cc]][0]) = bR[cc];
        __syncthreads();
        // prefetch next iteration (flies during MFMA below)
        h8_t aN[4], bN[4];
        bool more = (kt + 32) < K;
        if (more) {
            aoff += aStep; kqbase += bStep;
            aN[0] = *reinterpret_cast<const h8_t*>(Ah + aoff);
            aN[1] = *reinterpret_cast<const h8_t*>(Ah + aoff + 128);
            aN[2] = *reinterpret_cast<const h8_t*>(Al + aoff);
            aN[3] = *reinterpret_cast<const h8_t*>(Al + aoff + 128);
#pragma unroll
            for (int cc = 0; cc < 4; cc++)
                bN[cc] = *reinterpret_cast<const h8_t*>(sBase[cc] + kqbase);
        }
#pragma unroll
        for (int c = 0; c < 8; c++) {
            h8_t bh = *reinterpret_cast<const h8_t*>(&Bs[0][quad][c * 16 + m16][0]);
            h8_t bl = *reinterpret_cast<const h8_t*>(&Bs[1][quad][c * 16 + m16][0]);
            acc[0][c] = __builtin_amdgcn_mfma_f32_16x16x32_f16(aR[0], bh, acc[0][c], 0, 0, 0);
            acc[1][c] = __builtin_amdgcn_mfma_f32_16x16x32_f16(aR[1], bh, acc[1][c], 0, 0, 0);
            acc[0][c] = __builtin_amdgcn_mfma_f32_16x16x32_f16(aR[0], bl, acc[0][c], 0, 0, 0);
            acc[1][c] = __builtin_amdgcn_mfma_f32_16x16x32_f16(aR[1], bl, acc[1][c], 0, 0, 0);
            acc[0][c] = __builtin_amdgcn_mfma_f32_16x16x32_f16(aR[2], bh, acc[0][c], 0, 0, 0);
            acc[1][c] = __builtin_amdgcn_mfma_f32_16x16x32_f16(aR[3], bh, acc[1][c], 0, 0, 0);
        }
        __syncthreads();
        if (more) {
#pragma unroll
            for (int j = 0; j < 4; j++) { aR[j] = aN[j]; bR[j] = bN[j]; }
        }
    }

    float asv[8], adv[8];
#pragma unroll
    for (int c = 0; c < 8; c++) {
        asv[c] = a_src[colBase + c * 16 + m16];
        adv[c] = a_dst[colBase + c * 16 + m16];
    }
    int hb = colBase >> 6;
#pragma unroll
    for (int t = 0; t < 2; t++) {
#pragma unroll
        for (int i = 0; i < 4; i++) {
            int r = row0 + t * 16 + quad * 4 + i;
            float s0 = 0.f, d0 = 0.f, s1 = 0.f, d1 = 0.f;
#pragma unroll
            for (int c = 0; c < 8; c++) {
                float v = acc[t][c][i];
                if (c < 4) { s0 += v * asv[c]; d0 += v * adv[c]; }
                else       { s1 += v * asv[c]; d1 += v * adv[c]; }
            }
#pragma unroll
            for (int off = 1; off < 16; off <<= 1) {
                s0 += __shfl_xor(s0, off);
                d0 += __shfl_xor(d0, off);
                s1 += __shfl_xor(s1, off);
                d1 += __shfl_xor(d1, off);
            }
            if (m16 == 0 && r < M) {
                aS[r * 4 + hb] = s0;     aD[r * 4 + hb] = d0;
                aS[r * 4 + hb + 1] = s1; aD[r * 4 + hb + 1] = d1;
            }
        }
    }

    // wave-local epilogue (no barriers)
#pragma unroll
    for (int t = 0; t < 2; t++) {
#pragma unroll
        for (int c = 0; c < 8; c++)
#pragma unroll
            for (int i = 0; i < 4; i++)
                st[wv][quad * 4 + i][c * 16 + m16] = (_Float16)acc[t][c][i];
        int rowChunk = row0 + t * 16;
#pragma unroll
        for (int it = 0; it < 4; it++) {
            int lid = it * 64 + lane;
            int rloc = lid >> 4, u = lid & 15;
            h8_t v = *reinterpret_cast<const h8_t*>(&st[wv][rloc][u * 8]);
            *reinterpret_cast<h8_t*>(hOut + (size_t)(rowChunk + rloc) * 256 + colBase + u * 8) = v;
        }
    }
}

// ---------------- layer-2 GEMM: 64-row blocks (was 1.5 blocks/CU) ----------------
__global__ __launch_bounds__(256) void gemm_l2_kernel(
        const _Float16* __restrict__ Ah, const _Float16* __restrict__ Al,
        const _Float16* __restrict__ Bh, const _Float16* __restrict__ Bl,
        const float* __restrict__ a_src, const float* __restrict__ a_dst,
        _Float16* __restrict__ hOut, float* __restrict__ aS, float* __restrict__ aD,
        int Mpad, int M, int K) {
    const int Nn = 64;
    __shared__ _Float16 Bs[2][4][64][8];
    __shared__ _Float16 st[4][16][72];
    int tid = threadIdx.x;
    int wv = tid >> 6, lane = tid & 63;
    int m16 = lane & 15, quad = lane >> 4;
    int row0 = blockIdx.x * 64 + wv * 16;

    floatx4 acc[4];
#pragma unroll
    for (int c = 0; c < 4; c++)
#pragma unroll
        for (int i = 0; i < 4; i++) acc[c][i] = 0.f;

    int sPlane[2], sQ[2], sCol[2];
    const _Float16* sBase[2];
#pragma unroll
    for (int cc = 0; cc < 2; cc++) {
        int c = tid + cc * 256;
        sPlane[cc] = c >> 8;
        int rem = c & 255;
        sQ[cc] = rem >> 6;
        sCol[cc] = rem & 63;
        sBase[cc] = (sPlane[cc] ? Bl : Bh) + ((size_t)sQ[cc] * Nn + sCol[cc]) * 8;
    }

    size_t aoff = ((size_t)quad * Mpad + row0 + m16) * 8;
    size_t kqbase = 0;
    const size_t aStep = (size_t)Mpad * 32;
    const size_t bStep = (size_t)Nn * 32;

    h8_t aR[2], bR[2];
    aR[0] = *reinterpret_cast<const h8_t*>(Ah + aoff);
    aR[1] = *reinterpret_cast<const h8_t*>(Al + aoff);
#pragma unroll
    for (int cc = 0; cc < 2; cc++)
        bR[cc] = *reinterpret_cast<const h8_t*>(sBase[cc] + kqbase);

    for (int kt = 0; kt < K; kt += 32) {
#pragma unroll
        for (int cc = 0; cc < 2; cc++)
            *reinterpret_cast<h8_t*>(&Bs[sPlane[cc]][sQ[cc]][sCol[cc]][0]) = bR[cc];
        __syncthreads();
        h8_t aN[2], bN[2];
        bool more = (kt + 32) < K;
        if (more) {
            aoff += aStep; kqbase += bStep;
            aN[0] = *reinterpret_cast<const h8_t*>(Ah + aoff);
            aN[1] = *reinterpret_cast<const h8_t*>(Al + aoff);
#pragma unroll
            for (int cc = 0; cc < 2; cc++)
                bN[cc] = *reinterpret_cast<const h8_t*>(sBase[cc] + kqbase);
        }
#pragma unroll
        for (int c = 0; c < 4; c++) {
            h8_t bh = *reinterpret_cast<const h8_t*>(&Bs[0][quad][c * 16 + m16][0]);
            h8_t bl = *reinterpret_cast<const h8_t*>(&Bs[1][quad][c * 16 + m16][0]);
            acc[c] = __builtin_amdgcn_mfma_f32_16x16x32_f16(aR[0], bh, acc[c], 0, 0, 0);
            acc[c] = __builtin_amdgcn_mfma_f32_16x16x32_f16(aR[0], bl, acc[c], 0, 0, 0);
            acc[c] = __builtin_amdgcn_mfma_f32_16x16x32_f16(aR[1], bh, acc[c], 0, 0, 0);
        }
        __syncthreads();
        if (more) {
            aR[0] = aN[0]; aR[1] = aN[1];
            bR[0] = bN[0]; bR[1] = bN[1];
        }
    }

    float asv[4], adv[4];
#pragma unroll
    for (int c = 0; c < 4; c++) {
        asv[c] = a_src[c * 16 + m16];
        adv[c] = a_dst[c * 16 + m16];
    }
#pragma unroll
    for (int i = 0; i < 4; i++) {
        int r = row0 + quad * 4 + i;
        float s0 = 0.f, d0 = 0.f;
#pragma unroll
        for (int c = 0; c < 4; c++) {
            float v = acc[c][i];
            s0 += v * asv[c]; d0 += v * adv[c];
        }
#pragma unroll
        for (int off = 1; off < 16; off <<= 1) {
            s0 += __shfl_xor(s0, off);
            d0 += __shfl_xor(d0, off);
        }
        if (m16 == 0 && r < M) { aS[r] = s0; aD[r] = d0; }
    }

    // wave-local epilogue (no barriers)
#pragma unroll
    for (int c = 0; c < 4; c++)
#pragma unroll
        for (int i = 0; i < 4; i++)
            st[wv][quad * 4 + i][c * 16 + m16] = (_Float16)acc[c][i];
#pragma unroll
    for (int it = 0; it < 2; it++) {
        int lid = it * 64 + lane;
        int rloc = lid >> 3, u = lid & 7;
        h8_t v = *reinterpret_cast<const h8_t*>(&st[wv][rloc][u * 8]);
        *reinterpret_cast<h8_t*>(hOut + (size_t)(row0 + rloc) * 64 + u * 8) = v;
    }
}

// ---------------- aggregation H=4 (R0 structure, plain loads) ----------------
template <int TAG>
__global__ __launch_bounds__(256) void aggregate4_kernel(const _Float16* __restrict__ hsrc,
                                                         const float* __restrict__ alpha_s,
                                                         const float* __restrict__ alpha_d,
                                                         const int* __restrict__ row_ptr,
                                                         const int* __restrict__ csr_src,
                                                         const float* __restrict__ bias,
                                                         _Float16* __restrict__ outH,
                                                         _Float16* __restrict__ outL,
                                                         int N, int Mpad) {
    __shared__ float wlds[4][64][4];
    __shared__ int   slds[4][64];
    int wv = threadIdx.x >> 6, lane = threadIdx.x & 63;
    int node = blockIdx.x * 4 + wv;
    if (node >= N) return;
    int rs = row_ptr[node], re = row_ptr[node + 1];
    int slot = lane >> 5, lp = lane & 31;
    int ghead = lp >> 3;
    int gbyte = lp * 16;
    float4 ad4 = *(const float4*)(alpha_d + (size_t)node * 4);

    float den0 = 0.f, den1 = 0.f, den2 = 0.f, den3 = 0.f;
    float acc8[8] = {0.f, 0.f, 0.f, 0.f, 0.f, 0.f, 0.f, 0.f};
    float* wp = &wlds[wv][0][0];
    int*   sp = &slds[wv][0];
    const char* hbase = (const char*)hsrc;
    for (int base = rs; base < re; base += 64) {
        int i = base + lane;
        float w0 = 0.f, w1 = 0.f, w2 = 0.f, w3 = 0.f;
        int off = 0;
        if (i < re) {
            int s = csr_src[i];
            float4 as = *(const float4*)(alpha_s + (size_t)s * 4);
            w0 = __expf(fminf(leaky(as.x + ad4.x), 60.f));
            w1 = __expf(fminf(leaky(as.y + ad4.y), 60.f));
            w2 = __expf(fminf(leaky(as.z + ad4.z), 60.f));
            w3 = __expf(fminf(leaky(as.w + ad4.w), 60.f));
            off = s * 512;
        }
        den0 += w0; den1 += w1; den2 += w2; den3 += w3;
        sp[lane] = off;
        *(float4*)(wp + lane * 4) = make_float4(w0, w1, w2, w3);
        int cnt = min(64, re - base);
#pragma unroll 2
        for (int j = slot; j < cnt; j += 2) {
            int o2 = sp[j];
            float w = wp[j * 4 + ghead];
            h8_t hv = *reinterpret_cast<const h8_t*>(hbase + o2 + gbyte);
#pragma unroll
            for (int k = 0; k < 8; k++) acc8[k] += w * (float)hv[k];
        }
    }
#pragma unroll
    for (int k = 0; k < 8; k++) acc8[k] += __shfl_xor(acc8[k], 32);
#pragma unroll
    for (int off = 32; off >= 1; off >>= 1) {
        den0 += __shfl_xor(den0, off);
        den1 += __shfl_xor(den1, off);
        den2 += __shfl_xor(den2, off);
        den3 += __shfl_xor(den3, off);
    }
    if (slot == 0) {
        float den = (ghead & 2) ? ((ghead & 1) ? den3 : den2) : ((ghead & 1) ? den1 : den0);
        float inv = 1.f / (den + 1e-16f);
        int cbase = lp * 8;
        float4 b0 = *(const float4*)(bias + cbase);
        float4 b1 = *(const float4*)(bias + cbase + 4);
        float bv[8] = {b0.x, b0.y, b0.z, b0.w, b1.x, b1.y, b1.z, b1.w};
        h8_t hv, lv;
#pragma unroll
        for (int k = 0; k < 8; k++) {
            float v = fmaxf(acc8[k] * inv + bv[k], 0.f);
            _Float16 hi = (_Float16)v;
            hv[k] = hi;
            lv[k] = (_Float16)(v - (float)hi);
        }
        size_t o = ((size_t)lp * Mpad + node) * 8;
        *reinterpret_cast<h8_t*>(outH + o) = hv;
        *reinterpret_cast<h8_t*>(outL + o) = lv;
    }
}

// ---------------- fused aggregation H=1 + head MLP ----------------
__global__ __launch_bounds__(256) void agg1_mlp_kernel(const _Float16* __restrict__ hsrc,
                                                       const float* __restrict__ alpha_s,
                                                       const float* __restrict__ alpha_d,
                                                       const int* __restrict__ row_ptr,
                                                       const int* __restrict__ csr_src,
                                                       const float* __restrict__ bias,
                                                       const float* __restrict__ Wo1,
                                                       const float* __restrict__ bo1,
                                                       const float* __restrict__ Wo2,
                                                       const float* __restrict__ bo2,
                                                       float* __restrict__ out, int N) {
    __shared__ float wlds[4][64];
    __shared__ int   slds[4][64];
    __shared__ float hrow[4][64];
    __shared__ float w1s[64 * 32];
    __shared__ float w2s[32];
    __shared__ float b1s[32];
    int tid = threadIdx.x;
#pragma unroll
    for (int i = 0; i < 8; i++) w1s[tid + i * 256] = Wo1[tid + i * 256];
    if (tid < 32) { w2s[tid] = Wo2[tid]; b1s[tid] = bo1[tid]; }
    __syncthreads();

    int wv = tid >> 6, lane = tid & 63;
    int node = blockIdx.x * 4 + wv;
    if (node >= N) return;
    int rs = row_ptr[node], re = row_ptr[node + 1];
    float ad = alpha_d[node];
    int slot = lane >> 3, lp = lane & 7;
    int gbyte = lp * 16;

    float den = 0.f;
    float acc8[8] = {0.f, 0.f, 0.f, 0.f, 0.f, 0.f, 0.f, 0.f};
    const char* hbase = (const char*)hsrc;
    float* wp = &wlds[wv][0];
    int*   sp = &slds[wv][0];
    for (int base = rs; base < re; base += 64) {
        int i = base + lane;
        float w = 0.f;
        int off = 0;
        if (i < re) {
            int s = csr_src[i];
            w = __expf(fminf(leaky(alpha_s[s] + ad), 60.f));
            off = s * 128;
        }
        den += w;
        sp[lane] = off;
        wp[lane] = w;
        int cnt = min(64, re - base);
#pragma unroll 2
        for (int j = slot; j < cnt; j += 8) {
            float wj = wp[j];
            h8_t hv = *reinterpret_cast<const h8_t*>(hbase + sp[j] + gbyte);
#pragma unroll
            for (int k = 0; k < 8; k++) acc8[k] += wj * (float)hv[k];
        }
    }
#pragma unroll
    for (int k = 0; k < 8; k++) {
        acc8[k] += __shfl_xor(acc8[k], 8);
        acc8[k] += __shfl_xor(acc8[k], 16);
        acc8[k] += __shfl_xor(acc8[k], 32);
    }
#pragma unroll
    for (int off = 32; off >= 1; off >>= 1) den += __shfl_xor(den, off);
    if (slot == 0) {
        float inv = 1.f / (den + 1e-16f);
        int cbase = lp * 8;
#pragma unroll
        for (int k = 0; k < 8; k++)
            hrow[wv][cbase + k] = acc8[k] * inv + bias[cbase + k];
    }
    int j = lane & 31;
    float a = b1s[j];
#pragma unroll 4
    for (int k = 0; k < 64; k++) a += hrow[wv][k] * w1s[k * 32 + j];
    a = fmaxf(a, 0.f);
    float p = a * w2s[j];
#pragma unroll
    for (int off = 16; off >= 1; off >>= 1) p += __shfl_xor(p, off);
    if (lane == 0) out[node] = p + bo2[0];
}

// ---------------- launch ----------------
extern "C" void kernel_launch(void* const* d_in, const int* in_sizes, int n_in,
                              void* d_out, int out_size, void* d_ws, size_t ws_size,
                              hipStream_t stream) {
    const float* x     = (const float*)d_in[0];
    const float* W_emb = (const float*)d_in[1];
    const float* b_emb = (const float*)d_in[2];
    const float* W0    = (const float*)d_in[3];
    const float* as0   = (const float*)d_in[4];
    const float* ad0   = (const float*)d_in[5];
    const float* b0    = (const float*)d_in[6];
    const float* W1    = (const float*)d_in[7];
    const float* as1   = (const float*)d_in[8];
    const float* ad1   = (const float*)d_in[9];
    const float* b1    = (const float*)d_in[10];
    const float* W2    = (const float*)d_in[11];
    const float* as2   = (const float*)d_in[12];
    const float* ad2   = (const float*)d_in[13];
    const float* b2    = (const float*)d_in[14];
    const float* Wo1   = (const float*)d_in[15];
    const float* bo1   = (const float*)d_in[16];
    const float* Wo2   = (const float*)d_in[17];
    const float* bo2   = (const float*)d_in[18];
    const int* eidx    = (const int*)d_in[19];

    const int N = in_sizes[0] / 128;
    const int E = in_sizes[19] / 2;
    const int* esrc = eidx;
    const int* edst = eidx + E;
    const int gmB   = (N + 127) / 128;
    const int Mpad  = gmB * 128;
    const int gmB64 = gmB * 2;   // 64-row blocks covering all of Mpad (padding rows deterministic)
    const int nb    = (N + 255) / 256;

    char* w = (char*)d_ws;
    auto alloc = [&](size_t bytes) {
        char* p = w;
        w += (bytes + 255) & ~(size_t)255;
        return (void*)p;
    };
    _Float16* hOut = (_Float16*)alloc((size_t)Mpad * 256 * 2);
    _Float16* PHh  = (_Float16*)alloc((size_t)Mpad * 256 * 2);
    _Float16* PHl  = (_Float16*)alloc((size_t)Mpad * 256 * 2);
    float* aS      = (float*)alloc((size_t)N * 4 * 4);
    float* aD      = (float*)alloc((size_t)N * 4 * 4);
    int*   row_ptr = (int*)alloc((size_t)(N + 1) * 4);
    int*   cursor  = (int*)alloc((size_t)N * 4);
    int*   cnt     = (int*)alloc((size_t)N * 4);
    int*   bsum    = (int*)alloc((size_t)nb * 4);
    int*   csr     = (int*)alloc((size_t)(E + N) * 4);
    _Float16* WeH  = (_Float16*)alloc(128 * 64 * 2);
    _Float16* WeL  = (_Float16*)alloc(128 * 64 * 2);
    _Float16* W0H  = (_Float16*)alloc(64 * 256 * 2);
    _Float16* W0L  = (_Float16*)alloc(64 * 256 * 2);
    _Float16* W1H  = (_Float16*)alloc(256 * 256 * 2);
    _Float16* W1L  = (_Float16*)alloc(256 * 256 * 2);
    _Float16* W2H  = (_Float16*)alloc(256 * 64 * 2);
    _Float16* W2L  = (_Float16*)alloc(256 * 64 * 2);

    // CSR build (multi-block scan)
    hipMemsetAsync(cnt, 0, (size_t)N * 4, stream);
    hist_kernel<<<(E + 255) / 256, 256, 0, stream>>>(edst, E, cnt);
    blocksum_kernel<<<nb, 256, 0, stream>>>(cnt, N, bsum);
    scanbsum_kernel<<<1, 256, 0, stream>>>(bsum, nb, row_ptr + N);
    rowptr_kernel<<<nb, 256, 0, stream>>>(cnt, bsum, N, row_ptr, cursor);
    scatter_kernel<<<(E + N + 255) / 256, 256, 0, stream>>>(esrc, edst, E, N, cursor, csr);

    // weight planes (fused single launch)
    prep_weights_all<<<dim3(256, 4), 256, 0, stream>>>(W_emb, W0, W1, W2,
                                                       WeH, WeL, W0H, W0L, W1H, W1L, W2H, W2L);

    int gn4 = (N + 3) / 4;

    // embedding (64-row blocks -> ~3 blocks/CU, full Mpad coverage)
    gemm_emb_kernel<<<dim3(gmB64, 1), 256, 0, stream>>>(x, WeH, WeL, b_emb, PHh, PHl, Mpad, N);

    // GAT layer 0
    gemm_gat0_kernel<<<dim3(gmB, 2), 256, 0, stream>>>(PHh, PHl, W0H, W0L, as0, ad0, hOut, aS, aD, Mpad, N);
    aggregate4_kernel<0><<<gn4, 256, 0, stream>>>(hOut, aS, aD, row_ptr, csr, b0, PHh, PHl, N, Mpad);

    // GAT layer 1
    gemm_gat1_kernel<<<dim3(gmB, 2), 256, 0, stream>>>(PHh, PHl, W1H, W1L, as1, ad1, hOut, aS, aD, Mpad, N, 256);
    aggregate4_kernel<1><<<gn4, 256, 0, stream>>>(hOut, aS, aD, row_ptr, csr, b1, PHh, PHl, N, Mpad);

    // GAT layer 2 (64-row blocks) + fused head MLP
    gemm_l2_kernel<<<dim3(gmB64, 1), 256, 0, stream>>>(PHh, PHl, W2H, W2L, as2, ad2, hOut, aS, aD, Mpad, N, 256);
    agg1_mlp_kernel<<<gn4, 256, 0, stream>>>(hOut, aS, aD, row_ptr, csr, b2,
                                             Wo1, bo1, Wo2, bo2, (float*)d_out, N);
}